// Round 1
// baseline (500.334 us; speedup 1.0000x reference)
//
#include <hip/hip_runtime.h>
#include <cstdint>
#include <cstddef>

#define BB 512
#define TT 8192
#define TW 256          // u32 spike words per sequence (TT/32)
#define KWIN 5

static __device__ __forceinline__ float fract_f(float x) {
#if __has_builtin(__builtin_amdgcn_fractf)
    return __builtin_amdgcn_fractf(x);
#else
    return x - floorf(x);
#endif
}

// ---------------------------------------------------------------------------
// Pass 1: serial LIF scan, one thread per (channel, batch) sequence.
// Spike bits (32 per u32, MSB-first within word) are stored in the first
// 768 floats of each row's sal region of d_out (overwritten by pass 2).
// Chain per step: fract(4) -> mul(4) -> add(4)  ~= 12 cyc, latency-bound.
// mul/add are UNFUSED to match numpy's two-rounding semantics exactly.
// ---------------------------------------------------------------------------
__global__ __launch_bounds__(256, 1)
void lif_scan_kernel(const float* __restrict__ amp,
                     const float* __restrict__ pitch,
                     const float* __restrict__ boundary,
                     const float* __restrict__ decay,
                     float* __restrict__ out)
{
    const int seq = blockIdx.x * 256 + threadIdx.x;   // 0..1535
    const int c = seq >> 9;                           // / 512
    const int b = seq & 511;

    const float* xrow = (c == 0 ? amp : (c == 1 ? pitch : boundary)) + (size_t)b * TT;
    const float dv = decay[c];

    // spike words live at row b's sal area: out + 512 + b*TT, words [c*TW .. c*TW+255]
    uint32_t* wout = reinterpret_cast<uint32_t*>(out + 512 + (size_t)b * TT) + c * TW;

    const float4* src = reinterpret_cast<const float4*>(xrow);  // 2048 float4

    // 4-deep prefetch ring: 4 iterations x 8 float4 (32 steps each)
    float4 buf[4][8];
#pragma unroll
    for (int j = 0; j < 4; ++j)
#pragma unroll
        for (int k = 0; k < 8; ++k)
            buf[j][k] = src[j * 8 + k];

    float v = 0.0f;

#define LIF_STEP(xx)                                            \
    {                                                           \
        float t2 = __fadd_rn(__fmul_rn(dv, v), (xx));           \
        float nv = fract_f(t2);                                 \
        bitsf = __builtin_fmaf(2.0f, bitsf, t2 - nv);           \
        v = nv;                                                 \
    }

    for (int it = 0; it < 256; it += 4) {
#pragma unroll
        for (int s = 0; s < 4; ++s) {
            float bitsf = 0.0f;
#pragma unroll
            for (int k = 0; k < 4; ++k) {
                float4 q = buf[s][k];
                LIF_STEP(q.x) LIF_STEP(q.y) LIF_STEP(q.z) LIF_STEP(q.w)
            }
            uint32_t hi = (uint32_t)bitsf;
            bitsf = 0.0f;
#pragma unroll
            for (int k = 4; k < 8; ++k) {
                float4 q = buf[s][k];
                LIF_STEP(q.x) LIF_STEP(q.y) LIF_STEP(q.z) LIF_STEP(q.w)
            }
            uint32_t lo = (uint32_t)bitsf;
            wout[it + s] = (hi << 16) | lo;

            // prefetch iteration it+s+4 (clamped; tail loads are harmless re-reads)
            int nxt = it + s + 4;
            if (nxt > 255) nxt = 255;
#pragma unroll
            for (int k = 0; k < 8; ++k)
                buf[s][k] = src[nxt * 8 + k];
        }
    }
#undef LIF_STEP
}

// ---------------------------------------------------------------------------
// Pass 2: per-row (512 blocks x 256 threads):
//   unpack spikes -> sal, row max, IEEE-divide normalize (bitwise == numpy),
//   coalesced float4 sal stores, exact tie-broken top-5 via u64-key max
//   reduction (key = mono(val_bits)<<32 | (8191 - t) => val desc, idx asc).
// ---------------------------------------------------------------------------
__global__ __launch_bounds__(256, 1)
void salience_topk_kernel(const float* __restrict__ weights,
                          float* __restrict__ out)
{
    const int b = blockIdx.x;
    const int tid = threadIdx.x;

    __shared__ uint32_t words[3 * TW];                 // 768 spike words
    __shared__ unsigned long long red[5];              // 4 wave partials + winner
    __shared__ float smax[4];

    float* sal_out = out + 512 + (size_t)b * TT;
    const uint32_t* wsrc = reinterpret_cast<const uint32_t*>(sal_out);

    words[tid]       = wsrc[tid];
    words[tid + 256] = wsrc[tid + 256];
    words[tid + 512] = wsrc[tid + 512];

    const float w0 = weights[0], w1 = weights[1], w2 = weights[2];
    __syncthreads();

    // each thread owns 32 t's: t = 4*tid + 1024*j + k, j in [0,8), k in [0,4)
    float sal[32];
    float vmax = -INFINITY;
#pragma unroll
    for (int j = 0; j < 8; ++j) {
        const int t0 = 4 * tid + 1024 * j;
        const int w  = t0 >> 5;
        const uint32_t wa = words[w];
        const uint32_t wp = words[TW + w];
        const uint32_t wq = words[2 * TW + w];
#pragma unroll
        for (int k = 0; k < 4; ++k) {
            const int sh = 31 - ((t0 & 31) + k);
            float s0 = (float)((wa >> sh) & 1u);
            float s1 = (float)((wp >> sh) & 1u);
            float s2 = (float)((wq >> sh) & 1u);
            float sv = __fadd_rn(__fadd_rn(__fmul_rn(w0, s0), __fmul_rn(w1, s1)),
                                 __fmul_rn(w2, s2));
            sal[j * 4 + k] = sv;
            vmax = fmaxf(vmax, sv);
        }
    }

    // block-wide max
#pragma unroll
    for (int off = 32; off; off >>= 1)
        vmax = fmaxf(vmax, __shfl_down(vmax, off));
    if ((tid & 63) == 0) smax[tid >> 6] = vmax;
    __syncthreads();
    const float denom = __fadd_rn(fmaxf(fmaxf(smax[0], smax[1]),
                                        fmaxf(smax[2], smax[3])), 1e-6f);

    // normalize with true IEEE division (matches numpy per-element), store sal,
    // and build u64 keys for exact tie-broken top-k.
    float norm[32];
    unsigned long long keys[32];
#pragma unroll
    for (int j = 0; j < 8; ++j) {
        const int t0 = 4 * tid + 1024 * j;
        float n0 = sal[j * 4 + 0] / denom;
        float n1 = sal[j * 4 + 1] / denom;
        float n2 = sal[j * 4 + 2] / denom;
        float n3 = sal[j * 4 + 3] / denom;
        norm[j * 4 + 0] = n0; norm[j * 4 + 1] = n1;
        norm[j * 4 + 2] = n2; norm[j * 4 + 3] = n3;
        *reinterpret_cast<float4*>(sal_out + t0) = make_float4(n0, n1, n2, n3);
#pragma unroll
        for (int k = 0; k < 4; ++k) {
            uint32_t ub = __float_as_uint(norm[j * 4 + k]);
            ub = (ub & 0x80000000u) ? ~ub : (ub | 0x80000000u);   // order-preserving
            keys[j * 4 + k] = ((unsigned long long)ub << 32)
                            | (unsigned long long)(uint32_t)(TT - 1 - (t0 + k));
        }
    }

    uint32_t excl = 0xFFFFFFFFu;   // per-thread valid mask over its 32 elements
    float vsum = 0.0f;

    for (int r = 0; r < KWIN; ++r) {
        unsigned long long best = 0ull;
#pragma unroll
        for (int i = 0; i < 32; ++i) {
            unsigned long long kk = ((excl >> i) & 1u) ? keys[i] : 0ull;
            if (kk > best) best = kk;
        }
#pragma unroll
        for (int off = 32; off; off >>= 1) {
            unsigned long long o = __shfl_down(best, off);
            if (o > best) best = o;
        }
        __syncthreads();                       // prev round's red[4] fully read
        if ((tid & 63) == 0) red[tid >> 6] = best;
        __syncthreads();
        if (tid == 0) {
            unsigned long long m = red[0];
            if (red[1] > m) m = red[1];
            if (red[2] > m) m = red[2];
            if (red[3] > m) m = red[3];
            red[4] = m;
        }
        __syncthreads();
        const unsigned long long wkey = red[4];
        const int t_win = TT - 1 - (int)(uint32_t)(wkey & 0xFFFFFFFFull);
        // decode winner's normalized value
        uint32_t hi = (uint32_t)(wkey >> 32);
        uint32_t fb = (hi & 0x80000000u) ? (hi & 0x7FFFFFFFu) : ~hi;
        const float fv = __uint_as_float(fb);

        // owner thread retires this element
        if (tid == ((t_win & 1023) >> 2)) {
            const int e = ((t_win >> 10) << 2) | (t_win & 3);
            excl &= ~(1u << e);
        }
        if (tid == 0) {
            vsum += fv;
            out[512 + (size_t)BB * TT + (size_t)b * KWIN + r] = (float)t_win;
        }
    }

    if (tid == 0) {
        const float avg = vsum / 5.0f;
        const float mu = 0.5f + 2.0f * tanhf(1.8f * avg);
        out[b] = mu;
    }
}

extern "C" void kernel_launch(void* const* d_in, const int* in_sizes, int n_in,
                              void* d_out, int out_size, void* d_ws, size_t ws_size,
                              hipStream_t stream) {
    const float* amp      = (const float*)d_in[0];
    const float* pitch    = (const float*)d_in[1];
    const float* boundary = (const float*)d_in[2];
    const float* decay    = (const float*)d_in[3];
    const float* weights  = (const float*)d_in[4];
    float* out = (float*)d_out;

    lif_scan_kernel<<<6, 256, 0, stream>>>(amp, pitch, boundary, decay, out);
    salience_topk_kernel<<<BB, 256, 0, stream>>>(weights, out);
}

// Round 2
// 228.243 us; speedup vs baseline: 2.1921x; 2.1921x over previous
//
#include <hip/hip_runtime.h>
#include <cstdint>
#include <cstddef>

#define BB 512
#define TT 8192
#define TW 256          // u32 spike words per sequence (TT/32)
#define KWIN 5
#define CH 64           // time steps per staged chunk
#define NCHK (TT / CH)  // 128
#define LSTR 65         // padded row stride (floats) of transposed LDS tile

static __device__ __forceinline__ float fract_f(float x) {
#if __has_builtin(__builtin_amdgcn_fractf)
    return __builtin_amdgcn_fractf(x);
#else
    return x - floorf(x);
#endif
}

// ---------------------------------------------------------------------------
// Pass 1: serial LIF scan. 24 blocks x 64 threads (ONE wave per block, so no
// barriers ever). Block handles 64 consecutive rows of one channel.
// Per 64-step chunk: 16 coalesced global_load_dwordx4 (4 rows x 256B each)
// -> regs -> transposed padded LDS tile[t][r] (stride 65: <=2-way banks both
// for scatter-writes and per-step reads). Double-buffered; loads issued 2
// chunks (~1600 cyc) ahead of consumption to cover HBM latency.
// Chain per step: mul(4)+add(4)+fract(4) ~= 12 cyc; mul/add UNFUSED to match
// numpy's two-rounding semantics bit-exactly (validated: absmax 0).
// ---------------------------------------------------------------------------
__global__ __launch_bounds__(64, 1)
void lif_scan_kernel(const float* __restrict__ amp,
                     const float* __restrict__ pitch,
                     const float* __restrict__ boundary,
                     const float* __restrict__ decay,
                     float* __restrict__ out)
{
    const int blk = blockIdx.x;        // 0..23
    const int l   = threadIdx.x;       // 0..63
    const int g0  = blk * 64;          // first flattened (c,b) row
    const int c   = g0 >> 9;           // channel
    const int b0  = g0 & 511;          // first batch row
    const float* __restrict__ base =
        (c == 0 ? amp : (c == 1 ? pitch : boundary)) + (size_t)b0 * TT;
    const float dv = decay[c];

    __shared__ float tile[2][CH * LSTR];   // 2 x 16.6 KB, transposed [t][r]

    const int lr = l >> 4;   // 0..3  (row group within a load instr)
    const int lc = l & 15;   // 0..15 (float4 column)

    float4 vbuf[16];         // 64 VGPRs staging buffer

    auto gload = [&](int ck) {
#pragma unroll
        for (int i = 0; i < 16; ++i) {
            const float* p = base + (size_t)(4 * i + lr) * TT + ck * CH + 4 * lc;
            vbuf[i] = *reinterpret_cast<const float4*>(p);
        }
    };
    auto dswrite = [&](int buf) {
        float* tb = tile[buf];
#pragma unroll
        for (int i = 0; i < 16; ++i) {
            const int r  = 4 * i + lr;
            const int t0 = 4 * lc;
            tb[(t0 + 0) * LSTR + r] = vbuf[i].x;   // banks (t0+r) mod 32: <=2-way
            tb[(t0 + 1) * LSTR + r] = vbuf[i].y;
            tb[(t0 + 2) * LSTR + r] = vbuf[i].z;
            tb[(t0 + 3) * LSTR + r] = vbuf[i].w;
        }
    };

    // spike words for row b0+l: first 768 floats of its sal region of d_out
    uint32_t* wout = reinterpret_cast<uint32_t*>(out + 512 + (size_t)(b0 + l) * TT)
                   + c * TW;

    // prologue: chunk0 -> LDS buf0; chunk1 in regs
    gload(0);
    dswrite(0);
    gload(1);

    float v = 0.0f;

#define LIF_STEP(xx)                                        \
    {                                                       \
        float t2 = __fadd_rn(__fmul_rn(dv, v), (xx));       \
        float nv = fract_f(t2);                             \
        bitsf = __builtin_fmaf(2.0f, bitsf, t2 - nv);       \
        v = nv;                                             \
    }

    for (int k = 0; k < NCHK; ++k) {
        const int cur = k & 1;
        if (k + 1 < NCHK) dswrite(cur ^ 1);   // regs(k+1) -> other LDS buffer
        if (k + 2 < NCHK) gload(k + 2);       // prefetch k+2 into regs

        const float* tb = tile[cur];
        uint32_t w0, w1;
        {
            float bitsf = 0.0f;
#pragma unroll
            for (int t = 0; t < 16; ++t) LIF_STEP(tb[t * LSTR + l]);
            uint32_t hi = (uint32_t)bitsf;
            bitsf = 0.0f;
#pragma unroll
            for (int t = 16; t < 32; ++t) LIF_STEP(tb[t * LSTR + l]);
            w0 = (hi << 16) | (uint32_t)bitsf;
        }
        {
            float bitsf = 0.0f;
#pragma unroll
            for (int t = 32; t < 48; ++t) LIF_STEP(tb[t * LSTR + l]);
            uint32_t hi = (uint32_t)bitsf;
            bitsf = 0.0f;
#pragma unroll
            for (int t = 48; t < 64; ++t) LIF_STEP(tb[t * LSTR + l]);
            w1 = (hi << 16) | (uint32_t)bitsf;
        }
        wout[2 * k]     = w0;
        wout[2 * k + 1] = w1;
    }
#undef LIF_STEP
}

// ---------------------------------------------------------------------------
// Pass 2: per-row (512 blocks x 256 threads):
//   unpack spikes -> sal, row max, IEEE-divide normalize (bitwise == numpy),
//   coalesced float4 sal stores, exact tie-broken top-5 via u64-key max
//   reduction (key = mono(val_bits)<<32 | (8191 - t) => val desc, idx asc).
// ---------------------------------------------------------------------------
__global__ __launch_bounds__(256, 1)
void salience_topk_kernel(const float* __restrict__ weights,
                          float* __restrict__ out)
{
    const int b = blockIdx.x;
    const int tid = threadIdx.x;

    __shared__ uint32_t words[3 * TW];                 // 768 spike words
    __shared__ unsigned long long red[5];              // 4 wave partials + winner
    __shared__ float smax[4];

    float* sal_out = out + 512 + (size_t)b * TT;
    const uint32_t* wsrc = reinterpret_cast<const uint32_t*>(sal_out);

    words[tid]       = wsrc[tid];
    words[tid + 256] = wsrc[tid + 256];
    words[tid + 512] = wsrc[tid + 512];

    const float w0 = weights[0], w1 = weights[1], w2 = weights[2];
    __syncthreads();

    // each thread owns 32 t's: t = 4*tid + 1024*j + k, j in [0,8), k in [0,4)
    float sal[32];
    float vmax = -INFINITY;
#pragma unroll
    for (int j = 0; j < 8; ++j) {
        const int t0 = 4 * tid + 1024 * j;
        const int w  = t0 >> 5;
        const uint32_t wa = words[w];
        const uint32_t wp = words[TW + w];
        const uint32_t wq = words[2 * TW + w];
#pragma unroll
        for (int k = 0; k < 4; ++k) {
            const int sh = 31 - ((t0 & 31) + k);
            float s0 = (float)((wa >> sh) & 1u);
            float s1 = (float)((wp >> sh) & 1u);
            float s2 = (float)((wq >> sh) & 1u);
            float sv = __fadd_rn(__fadd_rn(__fmul_rn(w0, s0), __fmul_rn(w1, s1)),
                                 __fmul_rn(w2, s2));
            sal[j * 4 + k] = sv;
            vmax = fmaxf(vmax, sv);
        }
    }

    // block-wide max
#pragma unroll
    for (int off = 32; off; off >>= 1)
        vmax = fmaxf(vmax, __shfl_down(vmax, off));
    if ((tid & 63) == 0) smax[tid >> 6] = vmax;
    __syncthreads();
    const float denom = __fadd_rn(fmaxf(fmaxf(smax[0], smax[1]),
                                        fmaxf(smax[2], smax[3])), 1e-6f);

    // normalize with true IEEE division (matches numpy per-element), store sal,
    // and build u64 keys for exact tie-broken top-k.
    float norm[32];
    unsigned long long keys[32];
#pragma unroll
    for (int j = 0; j < 8; ++j) {
        const int t0 = 4 * tid + 1024 * j;
        float n0 = sal[j * 4 + 0] / denom;
        float n1 = sal[j * 4 + 1] / denom;
        float n2 = sal[j * 4 + 2] / denom;
        float n3 = sal[j * 4 + 3] / denom;
        norm[j * 4 + 0] = n0; norm[j * 4 + 1] = n1;
        norm[j * 4 + 2] = n2; norm[j * 4 + 3] = n3;
        *reinterpret_cast<float4*>(sal_out + t0) = make_float4(n0, n1, n2, n3);
#pragma unroll
        for (int k = 0; k < 4; ++k) {
            uint32_t ub = __float_as_uint(norm[j * 4 + k]);
            ub = (ub & 0x80000000u) ? ~ub : (ub | 0x80000000u);   // order-preserving
            keys[j * 4 + k] = ((unsigned long long)ub << 32)
                            | (unsigned long long)(uint32_t)(TT - 1 - (t0 + k));
        }
    }

    uint32_t excl = 0xFFFFFFFFu;   // per-thread valid mask over its 32 elements
    float vsum = 0.0f;

    for (int r = 0; r < KWIN; ++r) {
        unsigned long long best = 0ull;
#pragma unroll
        for (int i = 0; i < 32; ++i) {
            unsigned long long kk = ((excl >> i) & 1u) ? keys[i] : 0ull;
            if (kk > best) best = kk;
        }
#pragma unroll
        for (int off = 32; off; off >>= 1) {
            unsigned long long o = __shfl_down(best, off);
            if (o > best) best = o;
        }
        __syncthreads();                       // prev round's red[4] fully read
        if ((tid & 63) == 0) red[tid >> 6] = best;
        __syncthreads();
        if (tid == 0) {
            unsigned long long m = red[0];
            if (red[1] > m) m = red[1];
            if (red[2] > m) m = red[2];
            if (red[3] > m) m = red[3];
            red[4] = m;
        }
        __syncthreads();
        const unsigned long long wkey = red[4];
        const int t_win = TT - 1 - (int)(uint32_t)(wkey & 0xFFFFFFFFull);
        // decode winner's normalized value
        uint32_t hi = (uint32_t)(wkey >> 32);
        uint32_t fb = (hi & 0x80000000u) ? (hi & 0x7FFFFFFFu) : ~hi;
        const float fv = __uint_as_float(fb);

        // owner thread retires this element
        if (tid == ((t_win & 1023) >> 2)) {
            const int e = ((t_win >> 10) << 2) | (t_win & 3);
            excl &= ~(1u << e);
        }
        if (tid == 0) {
            vsum += fv;
            out[512 + (size_t)BB * TT + (size_t)b * KWIN + r] = (float)t_win;
        }
    }

    if (tid == 0) {
        const float avg = vsum / 5.0f;
        const float mu = 0.5f + 2.0f * tanhf(1.8f * avg);
        out[b] = mu;
    }
}

extern "C" void kernel_launch(void* const* d_in, const int* in_sizes, int n_in,
                              void* d_out, int out_size, void* d_ws, size_t ws_size,
                              hipStream_t stream) {
    const float* amp      = (const float*)d_in[0];
    const float* pitch    = (const float*)d_in[1];
    const float* boundary = (const float*)d_in[2];
    const float* decay    = (const float*)d_in[3];
    const float* weights  = (const float*)d_in[4];
    float* out = (float*)d_out;

    lif_scan_kernel<<<24, 64, 0, stream>>>(amp, pitch, boundary, decay, out);
    salience_topk_kernel<<<BB, 256, 0, stream>>>(weights, out);
}

// Round 3
// 174.515 us; speedup vs baseline: 2.8670x; 1.3079x over previous
//
#include <hip/hip_runtime.h>
#include <cstdint>
#include <cstddef>

#define BB 512
#define TT 8192
#define TW 256          // u32 spike words per sequence (TT/32)
#define KWIN 5
#define CH 64           // time steps per staged chunk
#define NCHK (TT / CH)  // 128
#define RSTR 66         // LDS row stride in floats ([row][t] layout, 8B aligned, 2-way banks)
#define NSLOT 4         // LDS ring depth

static __device__ __forceinline__ float fract_f(float x) {
#if __has_builtin(__builtin_amdgcn_fractf)
    return __builtin_amdgcn_fractf(x);
#else
    return x - floorf(x);
#endif
}

// ---------------------------------------------------------------------------
// Pass 1: serial LIF scan, wave-specialized. 24 blocks x 128 threads:
//   wave 1 (tid 64..127) = loader: global float4 -> ds_write_b64 into 4-slot
//     LDS ring (chunk k lives in slot k&3), always 2 chunks ahead.
//   wave 0 (tid 0..63)   = compute: lane l owns row b0+l; per chunk reads
//     ds_read_b64 (bank 2l+t -> 2-way, free) issued a half-chunk ahead,
//     including a cross-barrier prefetch of chunk k+1's first half.
// Compute wave's DS queue holds ONLY reads -> no in-order write serialization.
// Chain per step: mul+add+fract (UNFUSED mul/add = numpy's two roundings,
// validated absmax 0). ~12 cyc/step chain, ~740 cyc/chunk issue -> chain-bound.
// ---------------------------------------------------------------------------
__global__ __launch_bounds__(128, 1)
void lif_scan_kernel(const float* __restrict__ amp,
                     const float* __restrict__ pitch,
                     const float* __restrict__ boundary,
                     const float* __restrict__ decay,
                     float* __restrict__ out)
{
    const int blk = blockIdx.x;        // 0..23
    const int tid = threadIdx.x;       // 0..127
    const int g0  = blk * 64;          // first flattened (c,b) row
    const int c   = g0 >> 9;
    const int b0  = g0 & 511;
    const float* __restrict__ base =
        (c == 0 ? amp : (c == 1 ? pitch : boundary)) + (size_t)b0 * TT;

    __shared__ float tile[NSLOT][CH * RSTR];   // 4 x 16.9 KB

    if (tid >= 64) {
        // ----------------- loader wave -----------------
        const int l1 = tid & 63;
        const int lr = l1 >> 4;    // 0..3
        const int lc = l1 & 15;    // 0..15
        float4 vbuf[16];

        auto gload = [&](int ck) {
#pragma unroll
            for (int i = 0; i < 16; ++i)
                vbuf[i] = *reinterpret_cast<const float4*>(
                    base + (size_t)(4 * i + lr) * TT + ck * CH + 4 * lc);
        };
        auto dsw = [&](int slot) {
            float* tb = tile[slot];
#pragma unroll
            for (int i = 0; i < 16; ++i) {
                float* d = &tb[(4 * i + lr) * RSTR + 4 * lc];
                *reinterpret_cast<float2*>(d)     = make_float2(vbuf[i].x, vbuf[i].y);
                *reinterpret_cast<float2*>(d + 2) = make_float2(vbuf[i].z, vbuf[i].w);
            }
        };

        gload(0); dsw(0);
        gload(1); dsw(1);
        __syncthreads();                           // B0: slots 0,1 ready
        for (int k = 0; k < NCHK; ++k) {
            if (k + 2 < NCHK) { gload(k + 2); dsw((k + 2) & 3); }
            __syncthreads();
        }
    } else {
        // ----------------- compute wave -----------------
        const int l = tid;
        const float dv = decay[c];
        uint32_t* wout = reinterpret_cast<uint32_t*>(out + 512 + (size_t)(b0 + l) * TT)
                       + c * TW;

        float2 A[16], B[16];
        float v = 0.0f;

        __syncthreads();                           // B0
        {   // prefetch first half of chunk 0
            const float* t0 = tile[0];
#pragma unroll
            for (int j = 0; j < 16; ++j)
                A[j] = *reinterpret_cast<const float2*>(&t0[l * RSTR + 2 * j]);
        }

#define LIF_STEP(xx)                                        \
        {                                                   \
            float t2 = __fadd_rn(__fmul_rn(dv, v), (xx));   \
            float nv = fract_f(t2);                         \
            bs = __builtin_fmaf(2.0f, bs, t2 - nv);         \
            v = nv;                                         \
        }

        for (int k = 0; k < NCHK; ++k) {
            const float* tb = tile[k & 3];
            // issue second-half reads now; chain on A needs no LDS wait
#pragma unroll
            for (int j = 0; j < 16; ++j)
                B[j] = *reinterpret_cast<const float2*>(&tb[l * RSTR + 32 + 2 * j]);

            uint32_t w0, w1;
            {
                float bs = 0.0f;
#pragma unroll
                for (int j = 0; j < 8; ++j) { LIF_STEP(A[j].x) LIF_STEP(A[j].y) }
                uint32_t hi = (uint32_t)bs;
                bs = 0.0f;
#pragma unroll
                for (int j = 8; j < 16; ++j) { LIF_STEP(A[j].x) LIF_STEP(A[j].y) }
                w0 = (hi << 16) | (uint32_t)bs;
            }
            // cross-barrier prefetch: first half of chunk k+1 (slot filled 2
            // barriers ago; loader won't overwrite it until chunk k+5)
            if (k + 1 < NCHK) {
                const float* tn = tile[(k + 1) & 3];
#pragma unroll
                for (int j = 0; j < 16; ++j)
                    A[j] = *reinterpret_cast<const float2*>(&tn[l * RSTR + 2 * j]);
            }
            {
                float bs = 0.0f;
#pragma unroll
                for (int j = 0; j < 8; ++j) { LIF_STEP(B[j].x) LIF_STEP(B[j].y) }
                uint32_t hi = (uint32_t)bs;
                bs = 0.0f;
#pragma unroll
                for (int j = 8; j < 16; ++j) { LIF_STEP(B[j].x) LIF_STEP(B[j].y) }
                w1 = (hi << 16) | (uint32_t)bs;
            }
            *reinterpret_cast<uint2*>(wout + 2 * k) = make_uint2(w0, w1);
            __syncthreads();
        }
#undef LIF_STEP
    }
}

// ---------------------------------------------------------------------------
// Pass 2: per-row (512 blocks x 256 threads), register-light (no spills):
//   sal has only 8 possible values (w . s, s in {0,1}^3) -> 8-entry table,
//   ONE IEEE divide per entry (bitwise == numpy's elementwise divide).
//   Streaming per-thread top-5 (5 u64 regs, sorted desc, branchless insert),
//   then 5 rounds of block-max with retire. Key = mono(val)<<32 | (8191-t)
//   => value desc, index asc (matches lax.top_k tie-breaking).
// ---------------------------------------------------------------------------
__global__ __launch_bounds__(256, 2)
void salience_topk_kernel(const float* __restrict__ weights,
                          float* __restrict__ out)
{
    const int b = blockIdx.x;
    const int tid = threadIdx.x;

    __shared__ uint32_t words[3 * TW];
    __shared__ float smax[4];
    __shared__ float ntab[8];
    __shared__ uint32_t htab[8];
    __shared__ unsigned long long red[4];
    __shared__ unsigned long long wins;

    float* sal_out = out + 512 + (size_t)b * TT;
    const uint32_t* wsrc = reinterpret_cast<const uint32_t*>(sal_out);

    words[tid]       = wsrc[tid];
    words[tid + 256] = wsrc[tid + 256];
    words[tid + 512] = wsrc[tid + 512];

    const float w0 = weights[0], w1 = weights[1], w2 = weights[2];
    __syncthreads();

    // pass 1: block max of sal
    float vmax = -INFINITY;
#pragma unroll
    for (int j = 0; j < 8; ++j) {
        const int t0 = 4 * tid + 1024 * j;
        const int wi = t0 >> 5;
        const uint32_t wa = words[wi], wp = words[TW + wi], wq = words[2 * TW + wi];
#pragma unroll
        for (int k = 0; k < 4; ++k) {
            const int sh = 31 - ((t0 & 31) + k);
            float s0 = (float)((wa >> sh) & 1u);
            float s1 = (float)((wp >> sh) & 1u);
            float s2 = (float)((wq >> sh) & 1u);
            float sv = __fadd_rn(__fadd_rn(__fmul_rn(w0, s0), __fmul_rn(w1, s1)),
                                 __fmul_rn(w2, s2));
            vmax = fmaxf(vmax, sv);
        }
    }
#pragma unroll
    for (int off = 32; off; off >>= 1)
        vmax = fmaxf(vmax, __shfl_down(vmax, off));
    if ((tid & 63) == 0) smax[tid >> 6] = vmax;
    __syncthreads();
    const float denom = __fadd_rn(fmaxf(fmaxf(smax[0], smax[1]),
                                        fmaxf(smax[2], smax[3])), 1e-6f);

    // 8-entry normalized-value + order-preserving-key tables
    if (tid < 8) {
        float s0 = (float)(tid & 1), s1 = (float)((tid >> 1) & 1), s2 = (float)(tid >> 2);
        float tv = __fadd_rn(__fadd_rn(__fmul_rn(w0, s0), __fmul_rn(w1, s1)),
                             __fmul_rn(w2, s2));
        float nv = tv / denom;                 // exact IEEE div, once per value
        ntab[tid] = nv;
        uint32_t ub = __float_as_uint(nv);
        htab[tid] = (ub & 0x80000000u) ? ~ub : (ub | 0x80000000u);
    }
    __syncthreads();

    // pass 2: store normalized sal + streaming per-thread top-5
    unsigned long long t5[5] = {0ull, 0ull, 0ull, 0ull, 0ull};  // sorted desc
#pragma unroll
    for (int j = 0; j < 8; ++j) {
        const int t0 = 4 * tid + 1024 * j;
        const int wi = t0 >> 5;
        const uint32_t wa = words[wi], wp = words[TW + wi], wq = words[2 * TW + wi];
        float4 q;
        float* qp = &q.x;
#pragma unroll
        for (int k = 0; k < 4; ++k) {
            const int sh = 31 - ((t0 & 31) + k);
            const uint32_t idx = ((wa >> sh) & 1u)
                               | (((wp >> sh) & 1u) << 1)
                               | (((wq >> sh) & 1u) << 2);
            qp[k] = ntab[idx];
            unsigned long long key = ((unsigned long long)htab[idx] << 32)
                                   | (unsigned long long)(uint32_t)(TT - 1 - (t0 + k));
            if (key > t5[4]) {
#pragma unroll
                for (int i = 0; i < 5; ++i) {
                    bool g = key > t5[i];
                    unsigned long long o = t5[i];
                    t5[i] = g ? key : o;
                    key   = g ? o : key;
                }
            }
        }
        *reinterpret_cast<float4*>(sal_out + t0) = q;
    }

    // 5 rounds: block max over per-thread heads, retire winner
    float vsum = 0.0f;
    for (int r = 0; r < KWIN; ++r) {
        unsigned long long cand = t5[0];
#pragma unroll
        for (int off = 32; off; off >>= 1) {
            unsigned long long o = __shfl_down(cand, off);
            if (o > cand) cand = o;
        }
        __syncthreads();
        if ((tid & 63) == 0) red[tid >> 6] = cand;
        __syncthreads();
        if (tid == 0) {
            unsigned long long m = red[0];
            if (red[1] > m) m = red[1];
            if (red[2] > m) m = red[2];
            if (red[3] > m) m = red[3];
            wins = m;
        }
        __syncthreads();
        const unsigned long long w = wins;
        if (t5[0] == w) {   // unique key -> exactly one thread retires it
            t5[0] = t5[1]; t5[1] = t5[2]; t5[2] = t5[3]; t5[3] = t5[4]; t5[4] = 0ull;
        }
        if (tid == 0) {
            uint32_t hi = (uint32_t)(w >> 32);
            uint32_t fb = (hi & 0x80000000u) ? (hi & 0x7FFFFFFFu) : ~hi;
            vsum += __uint_as_float(fb);
            out[512 + (size_t)BB * TT + (size_t)b * KWIN + r] =
                (float)(int)(TT - 1 - (uint32_t)(w & 0xFFFFFFFFull));
        }
    }

    if (tid == 0) {
        out[b] = 0.5f + 2.0f * tanhf(1.8f * (vsum / 5.0f));
    }
}

extern "C" void kernel_launch(void* const* d_in, const int* in_sizes, int n_in,
                              void* d_out, int out_size, void* d_ws, size_t ws_size,
                              hipStream_t stream) {
    const float* amp      = (const float*)d_in[0];
    const float* pitch    = (const float*)d_in[1];
    const float* boundary = (const float*)d_in[2];
    const float* decay    = (const float*)d_in[3];
    const float* weights  = (const float*)d_in[4];
    float* out = (float*)d_out;

    lif_scan_kernel<<<24, 128, 0, stream>>>(amp, pitch, boundary, decay, out);
    salience_topk_kernel<<<BB, 256, 0, stream>>>(weights, out);
}